// Round 1
// baseline (866.165 us; speedup 1.0000x reference)
//
#include <hip/hip_runtime.h>
#include <stdint.h>

// Problem constants (BinHD): samples [8192,10000] f32 {0,1}, classes [1000,10000] f32 {0,1}
// out [8192,1000] f32 = Hamming distance = popcount(xor) over bit-packed rows (exact).
#define N_ROWS 8192
#define C_CLS  1000
#define D_DIM  10000
#define W64P   160            // u64 words per packed row, padded (157 used, 3 zero)
#define W32P   (W64P * 2)     // 320 u32 words per packed row
#define BSTR   132            // B LDS row stride (words) — pads 128 to kill bank conflicts

// ---------------------------------------------------------------------------
// Kernel 1: bit-pack fp32 {0,1} rows into u64 words via wave ballot.
// One wave per row; each iteration: 64 coalesced float loads -> v_cmp -> ballot
// -> lane 0 stores one u64. Writes ALL W64P words (padding bits read as 0),
// so the 0xAA-poisoned workspace is fully initialized every call.
// ---------------------------------------------------------------------------
__global__ __launch_bounds__(256) void pack_kernel(
    const float* __restrict__ samples, const float* __restrict__ classes,
    unsigned long long* __restrict__ pA, unsigned long long* __restrict__ pB)
{
    int gwave = (blockIdx.x * 256 + threadIdx.x) >> 6;
    int lane  = threadIdx.x & 63;
    if (gwave >= N_ROWS + C_CLS) return;   // wave-uniform exit

    const float* src;
    unsigned long long* dst;
    if (gwave < N_ROWS) {
        src = samples + (size_t)gwave * D_DIM;
        dst = pA + (size_t)gwave * W64P;
    } else {
        int r = gwave - N_ROWS;
        src = classes + (size_t)r * D_DIM;
        dst = pB + (size_t)r * W64P;
    }

    #pragma unroll 4
    for (int w = 0; w < W64P; ++w) {
        int idx = w * 64 + lane;
        float v = 0.0f;
        if (idx < D_DIM) v = src[idx];
        unsigned long long m = __ballot(v > 0.5f);
        if (lane == 0) dst[w] = m;
    }
}

// ---------------------------------------------------------------------------
// Kernel 2: Hamming "GEMM": out[n,c] = sum_w popc(A[n,w] ^ B[c,w]).
// Block tile 128x128, 256 threads, 8x8 u32 accumulators per thread.
// K streamed in chunks of 16 u32 words through LDS.
//   A LDS: [128 rows][16 words], 16B-granule XOR swizzle keyed on (row>>3)&3
//          -> inner reads are 2-way max (free).
//   B LDS: transposed [16 kw][BSTR cols] -> uint4 read = 4 consecutive cols,
//          stride 132 -> conflict-free writes, 2-way reads.
// Per chunk per thread: 64 ds_read_b128 vs 2048 VALU (xor + bcnt-acc) => VALU-bound.
// ---------------------------------------------------------------------------
__global__ __launch_bounds__(256) void hd_kernel(
    const uint32_t* __restrict__ pA, const uint32_t* __restrict__ pB,
    float* __restrict__ out)
{
    __shared__ uint32_t As[128 * 16];
    __shared__ uint32_t Bs[16 * BSTR];

    const int tid  = threadIdx.x;
    const int row0 = blockIdx.x * 128;   // 64 row tiles
    const int col0 = blockIdx.y * 128;   // 8 col tiles (1024 padded cols)

    const int w    = tid >> 6;           // wave 0..3
    const int lane = tid & 63;
    const int lx   = lane & 7;           // col octet within wave tile
    const int ly   = lane >> 3;          // row octet within wave tile
    const int wx   = w & 1, wy = w >> 1;
    const int trow = wy * 64 + ly * 8;   // thread row base in 128-tile
    const int tcol = wx * 64 + lx * 8;   // thread col base in 128-tile
    const int sw   = ly & 3;             // A read swizzle key ((row>>3)&3 for our rows)

    uint32_t acc[8][8];
    #pragma unroll
    for (int r = 0; r < 8; ++r)
        #pragma unroll
        for (int c = 0; c < 8; ++c) acc[r][c] = 0;

    for (int ch = 0; ch < 20; ++ch) {
        // ---- global loads for this chunk (before barrier, hides latency) ----
        uint4 av[2], bv[2];
        #pragma unroll
        for (int i = 0; i < 2; ++i) {
            int u  = tid + 256 * i;      // 0..511
            int rr = u >> 2;             // row/col in tile 0..127
            int g  = u & 3;              // 16B group 0..3
            av[i] = *(const uint4*)(pA + (size_t)(row0 + rr) * W32P + ch * 16 + g * 4);
            int gcol = col0 + rr;
            if (gcol < C_CLS)
                bv[i] = *(const uint4*)(pB + (size_t)gcol * W32P + ch * 16 + g * 4);
            else
                bv[i] = make_uint4(0u, 0u, 0u, 0u);
        }

        __syncthreads();   // previous chunk's LDS reads complete

        #pragma unroll
        for (int i = 0; i < 2; ++i) {
            int u  = tid + 256 * i;
            int rr = u >> 2;
            int g  = u & 3;
            // A: swizzled 16B-granule store
            *(uint4*)&As[rr * 16 + ((g ^ ((rr >> 3) & 3)) << 2)] = av[i];
            // B: transpose into [kw][col]
            Bs[(g * 4 + 0) * BSTR + rr] = bv[i].x;
            Bs[(g * 4 + 1) * BSTR + rr] = bv[i].y;
            Bs[(g * 4 + 2) * BSTR + rr] = bv[i].z;
            Bs[(g * 4 + 3) * BSTR + rr] = bv[i].w;
        }

        __syncthreads();   // LDS tile ready

        #pragma unroll
        for (int g = 0; g < 4; ++g) {
            uint4 a[8];
            #pragma unroll
            for (int r = 0; r < 8; ++r)
                a[r] = *(const uint4*)&As[(trow + r) * 16 + ((g ^ sw) << 2)];
            uint4 b0[4], b1[4];
            #pragma unroll
            for (int j = 0; j < 4; ++j) {
                b0[j] = *(const uint4*)&Bs[(g * 4 + j) * BSTR + tcol];
                b1[j] = *(const uint4*)&Bs[(g * 4 + j) * BSTR + tcol + 4];
            }
            #pragma unroll
            for (int r = 0; r < 8; ++r) {
                #pragma unroll
                for (int j = 0; j < 4; ++j) {
                    uint32_t aw = (j == 0) ? a[r].x : (j == 1) ? a[r].y
                                : (j == 2) ? a[r].z : a[r].w;
                    acc[r][0] += __popc(aw ^ b0[j].x);
                    acc[r][1] += __popc(aw ^ b0[j].y);
                    acc[r][2] += __popc(aw ^ b0[j].z);
                    acc[r][3] += __popc(aw ^ b0[j].w);
                    acc[r][4] += __popc(aw ^ b1[j].x);
                    acc[r][5] += __popc(aw ^ b1[j].y);
                    acc[r][6] += __popc(aw ^ b1[j].z);
                    acc[r][7] += __popc(aw ^ b1[j].w);
                }
            }
        }
    }

    // ---- epilogue: exact integer -> f32, float4 stores (1000 % 4 == 0) ----
    #pragma unroll
    for (int r = 0; r < 8; ++r) {
        int grow = row0 + trow + r;
        #pragma unroll
        for (int c4 = 0; c4 < 2; ++c4) {
            int gcol = col0 + tcol + c4 * 4;
            if (gcol < C_CLS) {
                float4 v = make_float4((float)acc[r][c4 * 4 + 0],
                                       (float)acc[r][c4 * 4 + 1],
                                       (float)acc[r][c4 * 4 + 2],
                                       (float)acc[r][c4 * 4 + 3]);
                *(float4*)(out + (size_t)grow * C_CLS + gcol) = v;
            }
        }
    }
}

extern "C" void kernel_launch(void* const* d_in, const int* in_sizes, int n_in,
                              void* d_out, int out_size, void* d_ws, size_t ws_size,
                              hipStream_t stream) {
    const float* samples = (const float*)d_in[0];   // [8192, 10000] f32
    const float* classes = (const float*)d_in[1];   // [1000, 10000] f32
    float* out = (float*)d_out;                     // [8192, 1000] f32

    // Workspace layout: packed A (8192*160 u64 = 10.49 MB) then packed B (1.28 MB)
    unsigned long long* pA = (unsigned long long*)d_ws;
    unsigned long long* pB = pA + (size_t)N_ROWS * W64P;

    int waves  = N_ROWS + C_CLS;             // one wave per row
    int blocks = (waves + 3) / 4;            // 4 waves per 256-thread block
    pack_kernel<<<blocks, 256, 0, stream>>>(samples, classes, pA, pB);

    dim3 grid(N_ROWS / 128, 8);              // 64 x 8 = 512 blocks (2 per CU)
    hd_kernel<<<grid, 256, 0, stream>>>((const uint32_t*)pA, (const uint32_t*)pB, out);
}